// Round 14
// baseline (161.834 us; speedup 1.0000x reference)
//
#include <hip/hip_runtime.h>

#define B_  2
#define S_  2048
#define E_  1024
#define H_  16
#define D_  64
#define NGLOB 2
#define NRAND 3
#define WIN 3

typedef __bf16 bf16x8 __attribute__((ext_vector_type(8)));
typedef float  f32x4  __attribute__((ext_vector_type(4)));

__device__ __forceinline__ unsigned short f2bf(float f) {
    unsigned u = __builtin_bit_cast(unsigned, f);
    unsigned r = u + 0x7FFFu + ((u >> 16) & 1u);   // RNE
    return (unsigned short)(r >> 16);
}
__device__ __forceinline__ float bf2f(unsigned short u) {
    return __builtin_bit_cast(float, (unsigned)u << 16);
}

// async global->LDS 16B DMA. LDS dest is wave-uniform base + lane*16.
__device__ __forceinline__ void g2l16(const unsigned short* g, unsigned short* l) {
    __builtin_amdgcn_global_load_lds(
        (const __attribute__((address_space(1))) unsigned*)g,
        (__attribute__((address_space(3))) unsigned*)l, 16, 0, 0);
}

// ---------------- fused fp32 -> bf16 conversion for x + 4 weights ----------------
__global__ __launch_bounds__(256)
void convert_all(const float* __restrict__ x,  const float* __restrict__ qw,
                 const float* __restrict__ kw, const float* __restrict__ vw,
                 const float* __restrict__ ow,
                 unsigned short* __restrict__ xb, unsigned short* __restrict__ wqkv,
                 unsigned short* __restrict__ wo) {
    const int XN = (B_ * S_ * E_) / 4;      // 1048576
    const int WN = (E_ * E_) / 4;           // 262144
    int i = blockIdx.x * blockDim.x + threadIdx.x;
    int r, loc;
    if (i < XN) { r = 0; loc = i; }
    else        { int j = i - XN; r = 1 + (j >> 18); loc = j & (WN - 1); }
    const float* src = r == 0 ? x : r == 1 ? qw : r == 2 ? kw : r == 3 ? vw : ow;
    float4 f = ((const float4*)src)[loc];
    ushort4 u;
    u.x = f2bf(f.x); u.y = f2bf(f.y); u.z = f2bf(f.z); u.w = f2bf(f.w);
    ushort4* dst = r == 0 ? (ushort4*)xb : r == 4 ? (ushort4*)wo
                 : (ushort4*)wqkv + (size_t)(r - 1) * WN;
    dst[loc] = u;
}

// ---------------- QKV GEMM: BK=64, XOR-swizzled LDS (known-good) ------------------
__global__ __launch_bounds__(256, 3)
void gemm_qkv(const unsigned short* __restrict__ A,  // [M][K] bf16
              const unsigned short* __restrict__ W,  // [N][K] bf16
              const float* __restrict__ b0, const float* __restrict__ b1,
              const float* __restrict__ b2,
              unsigned short* __restrict__ Cb, int M, int N, int K) {
    __shared__ unsigned short sA[128 * 64];   // 16 KB
    __shared__ unsigned short sB[128 * 64];   // 16 KB
    const int t = threadIdx.x;
    const int lane = t & 63;
    const int wave = t >> 6;
    const int wm = wave >> 1, wn = wave & 1;
    const int lq = lane >> 4;
    const int lr = lane & 15;
    const int bm = blockIdx.x * 128;
    const int bn = blockIdx.y * 128;

    f32x4 acc[4][4] = {};

    for (int k0 = 0; k0 < K; k0 += 64) {
        const unsigned short* Abase = A + (size_t)bm * K + k0;
        const unsigned short* Wbase = W + (size_t)bn * K + k0;
        #pragma unroll
        for (int j = 0; j < 4; ++j) {             // 1024 chunks each
            int c = j * 256 + t;
            int row = c >> 3, cc = c & 7;
            int gcol = ((cc ^ (row & 7)) << 3);   // swizzled source col
            int dst = j * 2048 + wave * 512;      // wave-uniform elem offset
            g2l16(Abase + (size_t)row * K + gcol, sA + dst);
            g2l16(Wbase + (size_t)row * K + gcol, sB + dst);
        }
        __syncthreads();

        #pragma unroll
        for (int ks = 0; ks < 2; ++ks) {
            const int sw = (((ks << 2) + lq) ^ (lr & 7)) << 3;
            bf16x8 af[4], bfr[4];
            #pragma unroll
            for (int i = 0; i < 4; ++i)
                af[i] = *(const bf16x8*)&sA[(wm * 64 + i * 16 + lr) * 64 + sw];
            #pragma unroll
            for (int j = 0; j < 4; ++j)
                bfr[j] = *(const bf16x8*)&sB[(wn * 64 + j * 16 + lr) * 64 + sw];
            #pragma unroll
            for (int i = 0; i < 4; ++i)
                #pragma unroll
                for (int j = 0; j < 4; ++j)
                    acc[i][j] = __builtin_amdgcn_mfma_f32_16x16x32_bf16(af[i], bfr[j], acc[i][j], 0, 0, 0);
        }
        __syncthreads();
    }

    #pragma unroll
    for (int i = 0; i < 4; ++i) {
        int row0 = bm + wm * 64 + i * 16 + lq * 4;
        #pragma unroll
        for (int j = 0; j < 4; ++j) {
            int col = bn + wn * 64 + j * 16 + lr;
            const float* bp = col < E_ ? b0 : (col < 2 * E_ ? b1 : b2);
            float bv = bp[col & (E_ - 1)];
            #pragma unroll
            for (int r = 0; r < 4; ++r)
                Cb[(size_t)(row0 + r) * N + col] = f2bf(acc[i][j][r] + bv);
        }
    }
}

// ---------------- O GEMM: 128x128 tile, fused global-row merge --------------------
// Blocks with bm==0 / bm==2048 (sole consumers of attn rows {0,1} per batch)
// first compute the 8-chunk merge for their 2 global rows (m==0 now -> plain sum),
// write bf16 to attn, vmcnt(0)+barrier, then stage normally (self-read through own
// L2). 8 blocks per batch redundantly write IDENTICAL bytes — benign.
__global__ __launch_bounds__(256, 3)
void gemm_o(unsigned short* A,                      // attn (read + global-row write)
            const unsigned short* __restrict__ W,   // [N][K] bf16 (wo)
            const float* __restrict__ bias,
            const float* __restrict__ gaccp, const float* __restrict__ gms,
            float* __restrict__ Cf, int M, int N, int K) {
    __shared__ unsigned short sA[128 * 64];   // 16 KB
    __shared__ unsigned short sB[128 * 64];   // 16 KB
    const int t = threadIdx.x;
    const int lane = t & 63;
    const int wave = t >> 6;
    const int wm = wave >> 1, wn = wave & 1;
    const int lq = lane >> 4;
    const int lr = lane & 15;
    const int bm = blockIdx.x * 128;
    const int bn = blockIdx.y * 128;

    // ---- fused gattn_fin for this tile's global rows ----
    if (blockIdx.x == 0 || blockIdx.x == 16) {
        int b = blockIdx.x >> 4;
        #pragma unroll
        for (int r = 0; r < 8; ++r) {
            int oid = r * 256 + t;              // 0..2047 : i2*1024 + col
            int i2 = oid >> 10, col = oid & 1023;
            int h = col >> 6, d = col & 63;
            int tup = b * 32 + i2 * 16 + h;
            float Mx = -1e30f;
            #pragma unroll
            for (int c = 0; c < 8; ++c) Mx = fmaxf(Mx, gms[(tup * 8 + c) * 2]);
            float den = 0.f, num = 0.f;
            #pragma unroll
            for (int c = 0; c < 8; ++c) {
                float f = __expf(gms[(tup * 8 + c) * 2] - Mx);
                den += gms[(tup * 8 + c) * 2 + 1] * f;
                num += gaccp[(size_t)(tup * 8 + c) * D_ + d] * f;
            }
            A[(size_t)(b * S_ + i2) * E_ + col] = f2bf(num / den);
        }
        asm volatile("s_waitcnt vmcnt(0)" ::: "memory");
    }
    __syncthreads();

    f32x4 acc[4][4] = {};

    for (int k0 = 0; k0 < K; k0 += 64) {
        const unsigned short* Abase = A + (size_t)bm * K + k0;
        const unsigned short* Wbase = W + (size_t)bn * K + k0;
        #pragma unroll
        for (int j = 0; j < 4; ++j) {
            int c = j * 256 + t;
            int row = c >> 3, cc = c & 7;
            int gcol = ((cc ^ (row & 7)) << 3);
            int dst = j * 2048 + wave * 512;
            g2l16(Abase + (size_t)row * K + gcol, sA + dst);
            g2l16(Wbase + (size_t)row * K + gcol, sB + dst);
        }
        __syncthreads();

        #pragma unroll
        for (int ks = 0; ks < 2; ++ks) {
            const int sw = (((ks << 2) + lq) ^ (lr & 7)) << 3;
            bf16x8 af[4], bfr[4];
            #pragma unroll
            for (int i = 0; i < 4; ++i)
                af[i] = *(const bf16x8*)&sA[(wm * 64 + i * 16 + lr) * 64 + sw];
            #pragma unroll
            for (int j = 0; j < 4; ++j)
                bfr[j] = *(const bf16x8*)&sB[(wn * 64 + j * 16 + lr) * 64 + sw];
            #pragma unroll
            for (int i = 0; i < 4; ++i)
                #pragma unroll
                for (int j = 0; j < 4; ++j)
                    acc[i][j] = __builtin_amdgcn_mfma_f32_16x16x32_bf16(af[i], bfr[j], acc[i][j], 0, 0, 0);
        }
        __syncthreads();
    }

    #pragma unroll
    for (int i = 0; i < 4; ++i) {
        int row0 = bm + wm * 64 + i * 16 + lq * 4;
        #pragma unroll
        for (int j = 0; j < 4; ++j) {
            int col = bn + wn * 64 + j * 16 + lr;
            float bv = bias[col];
            #pragma unroll
            for (int r = 0; r < 4; ++r)
                Cf[(size_t)(row0 + r) * N + col] = acc[i][j][r] + bv;
        }
    }
}

// ---------------- fused: streaming attn, ZERO-SHIFT softmax (R14) -----------------
// Softmax is shift-invariant; scores here are |s| <~ 3 (q,k ~ N(0,0.4^2), /sqrt(64))
// vs fp32 exp overflow at 88 — so use shift=0 instead of running max. This removes
// the online-rescale dependency chain: every key iteration is now fully
// INDEPENDENT {load K,V -> dot -> shfl -> exp -> fma}, letting the compiler
// pipeline all loads/exps. Masked candidates: __expf(-1e30) underflows to 0.
// gms m-slot written as 0 -> gemm_o merge degenerates to plain sum (unchanged code).
__global__ __launch_bounds__(256)
void attn_fused(const unsigned short* __restrict__ qkv,
                const int* __restrict__ rnd,
                float* __restrict__ gaccp, float* __restrict__ gms,
                unsigned short* __restrict__ attn) {
    const int NB = B_ * (S_ - 2);     // 4092
    int t = threadIdx.x;

    if (blockIdx.x < 512) {
        // ---- one (tuple, key-chunk) per block, single streaming pass ----
        int tup = blockIdx.x >> 3, seg = blockIdx.x & 7;
        int b = tup >> 5, i = (tup >> 4) & 1, h = tup & 15;
        int w = t >> 6, l = t & 63;
        __shared__ float reds[4];
        __shared__ float ov[4][D_];

        // q chunk for this lane: 8 bf16 dims (l&7)*8.. of the head slice
        const bf16x8* qp = (const bf16x8*)(qkv + (size_t)(b * S_ + i) * 3072 + h * D_);
        bf16x8 qv = qp[l & 7];
        float qreg[8];
        #pragma unroll
        for (int j = 0; j < 8; ++j) qreg[j] = (float)qv[j];

        // lane = (ksb key-sub, dg dim-group); wave w covers keys [key0, +64)
        const int key0 = seg * 256 + w * 64;
        const int ksb = l >> 3, dg = l & 7;
        float ssum = 0.f;
        float o[8] = {};
        #pragma unroll
        for (int it = 0; it < 8; ++it) {
            int key = key0 + it * 8 + ksb;
            const unsigned short* kr =
                qkv + (size_t)(b * S_ + key) * 3072 + E_ + h * D_ + dg * 8;
            bf16x8 kv = *(const bf16x8*)kr;          // K chunk
            bf16x8 vv = *(const bf16x8*)(kr + E_);   // V chunk, same key/dims
            float s = 0.f;
            #pragma unroll
            for (int j = 0; j < 8; ++j) s += qreg[j] * (float)kv[j];
            s += __shfl_xor(s, 1);
            s += __shfl_xor(s, 2);
            s += __shfl_xor(s, 4);
            float e = __expf(s * 0.125f);            // zero-shift softmax
            ssum += e;
            #pragma unroll
            for (int e2 = 0; e2 < 8; ++e2) o[e2] += e * (float)vv[e2];
        }
        // reduce over key-subs (masks vary ksb, keep dg)
        #pragma unroll
        for (int mask = 8; mask <= 32; mask <<= 1) {
            ssum += __shfl_xor(ssum, mask);
            #pragma unroll
            for (int e2 = 0; e2 < 8; ++e2) o[e2] += __shfl_xor(o[e2], mask);
        }
        if (l == 0) reds[w] = ssum;
        if (ksb == 0)
            #pragma unroll
            for (int e2 = 0; e2 < 8; ++e2) ov[w][dg * 8 + e2] = o[e2];
        __syncthreads();
        if (w == 0) {
            gaccp[((size_t)tup * 8 + seg) * D_ + l] =
                ov[0][l] + ov[1][l] + ov[2][l] + ov[3][l];
            if (l == 0) {
                gms[(tup * 8 + seg) * 2]     = 0.f;   // shift = 0
                gms[(tup * 8 + seg) * 2 + 1] = reds[0] + reds[1] + reds[2] + reds[3];
            }
        }
        return;
    }

    // ---- sparse rows: one wave per row, single streaming pass, zero-shift ----
    int bb = blockIdx.x - 512;                        // [0,1024)
    int bidx = (bb & 7) * 128 + (bb >> 3);            // XCD swizzle
    int w = t >> 6, l = t & 63;
    int row = bidx * 4 + w;
    bool valid = row < NB;
    int b = row / (S_ - 2);
    int i = row % (S_ - 2) + 2;
    if (!valid) { b = 0; i = 2; }

    __shared__ int cols_s[4][12];
    __shared__ int ncol_sh[4];

    const bf16x8* qp = (const bf16x8*)(qkv + (size_t)(b * S_ + i) * 3072);
    bf16x8 q0 = qp[l * 2], q1 = qp[l * 2 + 1];
    float qreg[16];
    #pragma unroll
    for (int j = 0; j < 8; ++j) { qreg[j] = (float)q0[j]; qreg[8 + j] = (float)q1[j]; }

    if (l == 0) {
        int* cols = cols_s[w];
        int n = 0;
        cols[n++] = 0; cols[n++] = 1;
        int lo = i - WIN; if (lo < NGLOB) lo = NGLOB;
        int hi = i + WIN; if (hi > S_ - 1) hi = S_ - 1;
        for (int j = lo; j <= hi; ++j) cols[n++] = j;
        for (int r = 0; r < NRAND; ++r) {
            int c = rnd[i * NRAND + r];
            bool dup = false;
            for (int q = 0; q < n; ++q) dup = dup || (cols[q] == c);
            if (!dup) cols[n++] = c;
        }
        ncol_sh[w] = n;
        for (int q = n; q < 12; ++q) cols[q] = 0;
    }
    __syncthreads();
    const int n = ncol_sh[w];

    // zero-shift streaming softmax: independent iterations, loads all in flight.
    float ssum = 0.f;
    float o[16] = {};
    #pragma unroll
    for (int c = 0; c < 12; ++c) {
        const unsigned short* base = qkv + (size_t)(b * S_ + cols_s[w][c]) * 3072 + E_;
        const bf16x8* kp = (const bf16x8*)base;
        bf16x8 k0 = kp[l * 2], k1 = kp[l * 2 + 1];
        const bf16x8* vp = (const bf16x8*)(base + E_);
        bf16x8 v0 = vp[l * 2], v1 = vp[l * 2 + 1];
        float s = 0.f;
        #pragma unroll
        for (int j = 0; j < 8; ++j) s += qreg[j] * (float)k0[j] + qreg[8 + j] * (float)k1[j];
        s += __shfl_xor(s, 1);
        s += __shfl_xor(s, 2);
        float e = (c < n) ? __expf(s * 0.125f) : 0.f;
        ssum += e;
        #pragma unroll
        for (int j = 0; j < 8; ++j) { o[j] += e * (float)v0[j]; o[8 + j] += e * (float)v1[j]; }
    }
    float inv = 1.f / ssum;
    #pragma unroll
    for (int j = 0; j < 16; ++j) o[j] *= inv;

    if (valid) {
        ushort4 u0, u1, u2, u3;
        u0.x = f2bf(o[0]);  u0.y = f2bf(o[1]);  u0.z = f2bf(o[2]);  u0.w = f2bf(o[3]);
        u1.x = f2bf(o[4]);  u1.y = f2bf(o[5]);  u1.z = f2bf(o[6]);  u1.w = f2bf(o[7]);
        u2.x = f2bf(o[8]);  u2.y = f2bf(o[9]);  u2.z = f2bf(o[10]); u2.w = f2bf(o[11]);
        u3.x = f2bf(o[12]); u3.y = f2bf(o[13]); u3.z = f2bf(o[14]); u3.w = f2bf(o[15]);
        ushort4* op = (ushort4*)(attn + (size_t)(b * S_ + i) * E_ + l * 16);
        op[0] = u0; op[1] = u1; op[2] = u2; op[3] = u3;
    }
}

extern "C" void kernel_launch(void* const* d_in, const int* in_sizes, int n_in,
                              void* d_out, int out_size, void* d_ws, size_t ws_size,
                              hipStream_t stream) {
    const float* x   = (const float*)d_in[0];
    const int*   rnd = (const int*)d_in[1];
    const float* qw  = (const float*)d_in[2];
    const float* qb  = (const float*)d_in[3];
    const float* kw  = (const float*)d_in[4];
    const float* kb  = (const float*)d_in[5];
    const float* vw  = (const float*)d_in[6];
    const float* vb  = (const float*)d_in[7];
    const float* ow  = (const float*)d_in[8];
    const float* ob  = (const float*)d_in[9];
    float* out = (float*)d_out;

    char* ws = (char*)d_ws;
    unsigned short* xb    = (unsigned short*)(ws);                       // 8 MB (dead after QKV GEMM)
    unsigned short* wqkv  = (unsigned short*)(ws + 8388608);             // 6 MB
    unsigned short* wo    = (unsigned short*)(ws + 14680064);            // 2 MB
    unsigned short* qkv   = (unsigned short*)(ws + 16777216);            // 24 MB
    unsigned short* attn  = (unsigned short*)(ws + 41943040);            // 8 MB
    float*          gaccp = (float*)(ws);                                // 128 KB (overlaps dead xb)
    float*          gms   = (float*)(ws + 131072);                       // 4 KB

    const int M = B_ * S_;   // 4096

    {
        int total4 = (M * E_ + 4 * E_ * E_) / 4;
        convert_all<<<total4 / 256, 256, 0, stream>>>(x, qw, kw, vw, ow, xb, wqkv, wo);
    }

    // QKV GEMM: [4096][3072] bf16, BK=64 swizzled, fully-resident grid
    {
        dim3 grid(M / 128, 3 * E_ / 128);
        gemm_qkv<<<grid, 256, 0, stream>>>(xb, wqkv, qb, kb, vb, qkv, M, 3 * E_, E_);
    }

    // global chunks (512, streaming zero-shift) + sparse rows (1024, streaming zero-shift)
    attn_fused<<<512 + 1024, 256, 0, stream>>>(qkv, rnd, gaccp, gms, attn);

    // O GEMM -> fp32 out, 128x128 tile, fused global-row merge (no fin dispatch)
    {
        dim3 grid(M / 128, E_ / 128);
        gemm_o<<<grid, 256, 0, stream>>>(attn, wo, ob, gaccp, gms, out, M, E_, E_);
    }
}

// Round 15
// 161.098 us; speedup vs baseline: 1.0046x; 1.0046x over previous
//
#include <hip/hip_runtime.h>

#define B_  2
#define S_  2048
#define E_  1024
#define H_  16
#define D_  64
#define NGLOB 2
#define NRAND 3
#define WIN 3

typedef __bf16 bf16x8 __attribute__((ext_vector_type(8)));
typedef float  f32x4  __attribute__((ext_vector_type(4)));

__device__ __forceinline__ unsigned short f2bf(float f) {
    unsigned u = __builtin_bit_cast(unsigned, f);
    unsigned r = u + 0x7FFFu + ((u >> 16) & 1u);   // RNE
    return (unsigned short)(r >> 16);
}
__device__ __forceinline__ float bf2f(unsigned short u) {
    return __builtin_bit_cast(float, (unsigned)u << 16);
}

// async global->LDS 16B DMA. LDS dest is wave-uniform base + lane*16.
__device__ __forceinline__ void g2l16(const unsigned short* g, unsigned short* l) {
    __builtin_amdgcn_global_load_lds(
        (const __attribute__((address_space(1))) unsigned*)g,
        (__attribute__((address_space(3))) unsigned*)l, 16, 0, 0);
}

// ---------------- fused fp32 -> bf16 conversion for x + 4 weights ----------------
__global__ __launch_bounds__(256)
void convert_all(const float* __restrict__ x,  const float* __restrict__ qw,
                 const float* __restrict__ kw, const float* __restrict__ vw,
                 const float* __restrict__ ow,
                 unsigned short* __restrict__ xb, unsigned short* __restrict__ wqkv,
                 unsigned short* __restrict__ wo) {
    const int XN = (B_ * S_ * E_) / 4;      // 1048576
    const int WN = (E_ * E_) / 4;           // 262144
    int i = blockIdx.x * blockDim.x + threadIdx.x;
    int r, loc;
    if (i < XN) { r = 0; loc = i; }
    else        { int j = i - XN; r = 1 + (j >> 18); loc = j & (WN - 1); }
    const float* src = r == 0 ? x : r == 1 ? qw : r == 2 ? kw : r == 3 ? vw : ow;
    float4 f = ((const float4*)src)[loc];
    ushort4 u;
    u.x = f2bf(f.x); u.y = f2bf(f.y); u.z = f2bf(f.z); u.w = f2bf(f.w);
    ushort4* dst = r == 0 ? (ushort4*)xb : r == 4 ? (ushort4*)wo
                 : (ushort4*)wqkv + (size_t)(r - 1) * WN;
    dst[loc] = u;
}

// ---------------- QKV GEMM: BK=64, XOR-swizzled LDS (known-good) ------------------
__global__ __launch_bounds__(256, 3)
void gemm_qkv(const unsigned short* __restrict__ A,  // [M][K] bf16
              const unsigned short* __restrict__ W,  // [N][K] bf16
              const float* __restrict__ b0, const float* __restrict__ b1,
              const float* __restrict__ b2,
              unsigned short* __restrict__ Cb, int M, int N, int K) {
    __shared__ unsigned short sA[128 * 64];   // 16 KB
    __shared__ unsigned short sB[128 * 64];   // 16 KB
    const int t = threadIdx.x;
    const int lane = t & 63;
    const int wave = t >> 6;
    const int wm = wave >> 1, wn = wave & 1;
    const int lq = lane >> 4;
    const int lr = lane & 15;
    const int bm = blockIdx.x * 128;
    const int bn = blockIdx.y * 128;

    f32x4 acc[4][4] = {};

    for (int k0 = 0; k0 < K; k0 += 64) {
        const unsigned short* Abase = A + (size_t)bm * K + k0;
        const unsigned short* Wbase = W + (size_t)bn * K + k0;
        #pragma unroll
        for (int j = 0; j < 4; ++j) {             // 1024 chunks each
            int c = j * 256 + t;
            int row = c >> 3, cc = c & 7;
            int gcol = ((cc ^ (row & 7)) << 3);   // swizzled source col
            int dst = j * 2048 + wave * 512;      // wave-uniform elem offset
            g2l16(Abase + (size_t)row * K + gcol, sA + dst);
            g2l16(Wbase + (size_t)row * K + gcol, sB + dst);
        }
        __syncthreads();

        #pragma unroll
        for (int ks = 0; ks < 2; ++ks) {
            const int sw = (((ks << 2) + lq) ^ (lr & 7)) << 3;
            bf16x8 af[4], bfr[4];
            #pragma unroll
            for (int i = 0; i < 4; ++i)
                af[i] = *(const bf16x8*)&sA[(wm * 64 + i * 16 + lr) * 64 + sw];
            #pragma unroll
            for (int j = 0; j < 4; ++j)
                bfr[j] = *(const bf16x8*)&sB[(wn * 64 + j * 16 + lr) * 64 + sw];
            #pragma unroll
            for (int i = 0; i < 4; ++i)
                #pragma unroll
                for (int j = 0; j < 4; ++j)
                    acc[i][j] = __builtin_amdgcn_mfma_f32_16x16x32_bf16(af[i], bfr[j], acc[i][j], 0, 0, 0);
        }
        __syncthreads();
    }

    #pragma unroll
    for (int i = 0; i < 4; ++i) {
        int row0 = bm + wm * 64 + i * 16 + lq * 4;
        #pragma unroll
        for (int j = 0; j < 4; ++j) {
            int col = bn + wn * 64 + j * 16 + lr;
            const float* bp = col < E_ ? b0 : (col < 2 * E_ ? b1 : b2);
            float bv = bp[col & (E_ - 1)];
            #pragma unroll
            for (int r = 0; r < 4; ++r)
                Cb[(size_t)(row0 + r) * N + col] = f2bf(acc[i][j][r] + bv);
        }
    }
}

// ---------------- O GEMM: 128x128 tile, fused global-row merge --------------------
// Blocks with bm==0 / bm==2048 (sole consumers of attn rows {0,1} per batch)
// first compute the 8-chunk flash merge for their 2 global rows, write bf16 to
// attn, vmcnt(0)+barrier, then stage normally (self-read through own L2).
// 8 blocks per batch redundantly write IDENTICAL bytes — benign.
__global__ __launch_bounds__(256, 3)
void gemm_o(unsigned short* A,                      // attn (read + global-row write)
            const unsigned short* __restrict__ W,   // [N][K] bf16 (wo)
            const float* __restrict__ bias,
            const float* __restrict__ gaccp, const float* __restrict__ gms,
            float* __restrict__ Cf, int M, int N, int K) {
    __shared__ unsigned short sA[128 * 64];   // 16 KB
    __shared__ unsigned short sB[128 * 64];   // 16 KB
    const int t = threadIdx.x;
    const int lane = t & 63;
    const int wave = t >> 6;
    const int wm = wave >> 1, wn = wave & 1;
    const int lq = lane >> 4;
    const int lr = lane & 15;
    const int bm = blockIdx.x * 128;
    const int bn = blockIdx.y * 128;

    // ---- fused gattn_fin for this tile's global rows ----
    if (blockIdx.x == 0 || blockIdx.x == 16) {
        int b = blockIdx.x >> 4;
        #pragma unroll
        for (int r = 0; r < 8; ++r) {
            int oid = r * 256 + t;              // 0..2047 : i2*1024 + col
            int i2 = oid >> 10, col = oid & 1023;
            int h = col >> 6, d = col & 63;
            int tup = b * 32 + i2 * 16 + h;
            float Mx = -1e30f;
            #pragma unroll
            for (int c = 0; c < 8; ++c) Mx = fmaxf(Mx, gms[(tup * 8 + c) * 2]);
            float den = 0.f, num = 0.f;
            #pragma unroll
            for (int c = 0; c < 8; ++c) {
                float f = __expf(gms[(tup * 8 + c) * 2] - Mx);
                den += gms[(tup * 8 + c) * 2 + 1] * f;
                num += gaccp[(size_t)(tup * 8 + c) * D_ + d] * f;
            }
            A[(size_t)(b * S_ + i2) * E_ + col] = f2bf(num / den);
        }
        asm volatile("s_waitcnt vmcnt(0)" ::: "memory");
    }
    __syncthreads();

    f32x4 acc[4][4] = {};

    for (int k0 = 0; k0 < K; k0 += 64) {
        const unsigned short* Abase = A + (size_t)bm * K + k0;
        const unsigned short* Wbase = W + (size_t)bn * K + k0;
        #pragma unroll
        for (int j = 0; j < 4; ++j) {
            int c = j * 256 + t;
            int row = c >> 3, cc = c & 7;
            int gcol = ((cc ^ (row & 7)) << 3);
            int dst = j * 2048 + wave * 512;
            g2l16(Abase + (size_t)row * K + gcol, sA + dst);
            g2l16(Wbase + (size_t)row * K + gcol, sB + dst);
        }
        __syncthreads();

        #pragma unroll
        for (int ks = 0; ks < 2; ++ks) {
            const int sw = (((ks << 2) + lq) ^ (lr & 7)) << 3;
            bf16x8 af[4], bfr[4];
            #pragma unroll
            for (int i = 0; i < 4; ++i)
                af[i] = *(const bf16x8*)&sA[(wm * 64 + i * 16 + lr) * 64 + sw];
            #pragma unroll
            for (int j = 0; j < 4; ++j)
                bfr[j] = *(const bf16x8*)&sB[(wn * 64 + j * 16 + lr) * 64 + sw];
            #pragma unroll
            for (int i = 0; i < 4; ++i)
                #pragma unroll
                for (int j = 0; j < 4; ++j)
                    acc[i][j] = __builtin_amdgcn_mfma_f32_16x16x32_bf16(af[i], bfr[j], acc[i][j], 0, 0, 0);
        }
        __syncthreads();
    }

    #pragma unroll
    for (int i = 0; i < 4; ++i) {
        int row0 = bm + wm * 64 + i * 16 + lq * 4;
        #pragma unroll
        for (int j = 0; j < 4; ++j) {
            int col = bn + wn * 64 + j * 16 + lr;
            float bv = bias[col];
            #pragma unroll
            for (int r = 0; r < 4; ++r)
                Cf[(size_t)(row0 + r) * N + col] = acc[i][j][r] + bv;
        }
    }
}

// ---------------- fused: streaming global chunks + streaming sparse rows ---------
// R13 (best measured, 159.8us): global path single streaming pass — per iter load
// K-chunk AND V-chunk together (16 loads, one in-flight window), 3-shfl score
// reduce, 3-shfl wave-max, online (mM, sum, o[8]) rescale; one key-sub shfl
// reduction, ONE barrier, 4-wave flash merge to gms/gaccp. Sparse path: one wave
// per row, single streaming pass with online softmax (group-uniform rescale).
__global__ __launch_bounds__(256)
void attn_fused(const unsigned short* __restrict__ qkv,
                const int* __restrict__ rnd,
                float* __restrict__ gaccp, float* __restrict__ gms,
                unsigned short* __restrict__ attn) {
    const int NB = B_ * (S_ - 2);     // 4092
    int t = threadIdx.x;

    if (blockIdx.x < 512) {
        // ---- one (tuple, key-chunk) per block, single streaming pass ----
        int tup = blockIdx.x >> 3, seg = blockIdx.x & 7;
        int b = tup >> 5, i = (tup >> 4) & 1, h = tup & 15;
        int w = t >> 6, l = t & 63;
        __shared__ float redm[4], reds[4];
        __shared__ float ov[4][D_];

        // q chunk for this lane: 8 bf16 dims (l&7)*8.. of the head slice
        const bf16x8* qp = (const bf16x8*)(qkv + (size_t)(b * S_ + i) * 3072 + h * D_);
        bf16x8 qv = qp[l & 7];
        float qreg[8];
        #pragma unroll
        for (int j = 0; j < 8; ++j) qreg[j] = (float)qv[j];

        // lane = (ksb key-sub, dg dim-group); wave w covers keys [key0, +64)
        const int key0 = seg * 256 + w * 64;
        const int ksb = l >> 3, dg = l & 7;
        float mM = -1e30f, ssum = 0.f;
        float o[8] = {};
        #pragma unroll
        for (int it = 0; it < 8; ++it) {
            int key = key0 + it * 8 + ksb;
            const unsigned short* kr =
                qkv + (size_t)(b * S_ + key) * 3072 + E_ + h * D_ + dg * 8;
            bf16x8 kv = *(const bf16x8*)kr;          // K chunk
            bf16x8 vv = *(const bf16x8*)(kr + E_);   // V chunk, same key/dims
            float s = 0.f;
            #pragma unroll
            for (int j = 0; j < 8; ++j) s += qreg[j] * (float)kv[j];
            s += __shfl_xor(s, 1);
            s += __shfl_xor(s, 2);
            s += __shfl_xor(s, 4);
            s *= 0.125f;                             // score for key it*8+ksb (all dg lanes)
            float m_it = s;
            m_it = fmaxf(m_it, __shfl_xor(m_it, 8));
            m_it = fmaxf(m_it, __shfl_xor(m_it, 16));
            m_it = fmaxf(m_it, __shfl_xor(m_it, 32));
            if (m_it > mM) {                         // wave-uniform
                float r = __expf(mM - m_it);
                ssum *= r;
                #pragma unroll
                for (int e2 = 0; e2 < 8; ++e2) o[e2] *= r;
                mM = m_it;
            }
            float e = __expf(s - mM);
            ssum += e;
            #pragma unroll
            for (int e2 = 0; e2 < 8; ++e2) o[e2] += e * (float)vv[e2];
        }
        // reduce over key-subs (masks vary ksb, keep dg)
        #pragma unroll
        for (int mask = 8; mask <= 32; mask <<= 1) {
            ssum += __shfl_xor(ssum, mask);
            #pragma unroll
            for (int e2 = 0; e2 < 8; ++e2) o[e2] += __shfl_xor(o[e2], mask);
        }
        if (l == 0) { redm[w] = mM; reds[w] = ssum; }
        if (ksb == 0)
            #pragma unroll
            for (int e2 = 0; e2 < 8; ++e2) ov[w][dg * 8 + e2] = o[e2];
        __syncthreads();
        if (w == 0) {
            float M = fmaxf(fmaxf(redm[0], redm[1]), fmaxf(redm[2], redm[3]));
            float f0 = __expf(redm[0] - M), f1 = __expf(redm[1] - M);
            float f2 = __expf(redm[2] - M), f3 = __expf(redm[3] - M);
            gaccp[((size_t)tup * 8 + seg) * D_ + l] =
                ov[0][l] * f0 + ov[1][l] * f1 + ov[2][l] * f2 + ov[3][l] * f3;
            if (l == 0) {
                gms[(tup * 8 + seg) * 2]     = M;
                gms[(tup * 8 + seg) * 2 + 1] =
                    reds[0] * f0 + reds[1] * f1 + reds[2] * f2 + reds[3] * f3;
            }
        }
        return;
    }

    // ---- sparse rows: one wave per row, single streaming pass ----
    int bb = blockIdx.x - 512;                        // [0,1024)
    int bidx = (bb & 7) * 128 + (bb >> 3);            // XCD swizzle
    int w = t >> 6, l = t & 63;
    int row = bidx * 4 + w;
    bool valid = row < NB;
    int b = row / (S_ - 2);
    int i = row % (S_ - 2) + 2;
    if (!valid) { b = 0; i = 2; }

    __shared__ int cols_s[4][12];
    __shared__ int ncol_sh[4];

    const bf16x8* qp = (const bf16x8*)(qkv + (size_t)(b * S_ + i) * 3072);
    bf16x8 q0 = qp[l * 2], q1 = qp[l * 2 + 1];
    float qreg[16];
    #pragma unroll
    for (int j = 0; j < 8; ++j) { qreg[j] = (float)q0[j]; qreg[8 + j] = (float)q1[j]; }

    if (l == 0) {
        int* cols = cols_s[w];
        int n = 0;
        cols[n++] = 0; cols[n++] = 1;
        int lo = i - WIN; if (lo < NGLOB) lo = NGLOB;
        int hi = i + WIN; if (hi > S_ - 1) hi = S_ - 1;
        for (int j = lo; j <= hi; ++j) cols[n++] = j;
        for (int r = 0; r < NRAND; ++r) {
            int c = rnd[i * NRAND + r];
            bool dup = false;
            for (int q = 0; q < n; ++q) dup = dup || (cols[q] == c);
            if (!dup) cols[n++] = c;
        }
        ncol_sh[w] = n;
        for (int q = n; q < 12; ++q) cols[q] = 0;
    }
    __syncthreads();
    const int n = ncol_sh[w];

    // streaming online-softmax: K and V of each candidate load together;
    // running (mM, ssum, o[16]) with 4-lane-group-uniform rescale.
    float mM = -1e30f, ssum = 0.f;
    float o[16] = {};
    #pragma unroll
    for (int c = 0; c < 12; ++c) {
        const unsigned short* base = qkv + (size_t)(b * S_ + cols_s[w][c]) * 3072 + E_;
        const bf16x8* kp = (const bf16x8*)base;
        bf16x8 k0 = kp[l * 2], k1 = kp[l * 2 + 1];
        const bf16x8* vp = (const bf16x8*)(base + E_);
        bf16x8 v0 = vp[l * 2], v1 = vp[l * 2 + 1];
        float s = 0.f;
        #pragma unroll
        for (int j = 0; j < 8; ++j) s += qreg[j] * (float)k0[j] + qreg[8 + j] * (float)k1[j];
        s += __shfl_xor(s, 1);
        s += __shfl_xor(s, 2);
        s = (c < n) ? s * 0.125f : -1e30f;
        if (s > mM) {                         // group-uniform (s identical in 4-lane group)
            float r = __expf(mM - s);
            ssum *= r;
            #pragma unroll
            for (int j = 0; j < 16; ++j) o[j] *= r;
            mM = s;
        }
        float e = __expf(s - mM);
        ssum += e;
        #pragma unroll
        for (int j = 0; j < 8; ++j) { o[j] += e * (float)v0[j]; o[8 + j] += e * (float)v1[j]; }
    }
    float inv = 1.f / ssum;
    #pragma unroll
    for (int j = 0; j < 16; ++j) o[j] *= inv;

    if (valid) {
        ushort4 u0, u1, u2, u3;
        u0.x = f2bf(o[0]);  u0.y = f2bf(o[1]);  u0.z = f2bf(o[2]);  u0.w = f2bf(o[3]);
        u1.x = f2bf(o[4]);  u1.y = f2bf(o[5]);  u1.z = f2bf(o[6]);  u1.w = f2bf(o[7]);
        u2.x = f2bf(o[8]);  u2.y = f2bf(o[9]);  u2.z = f2bf(o[10]); u2.w = f2bf(o[11]);
        u3.x = f2bf(o[12]); u3.y = f2bf(o[13]); u3.z = f2bf(o[14]); u3.w = f2bf(o[15]);
        ushort4* op = (ushort4*)(attn + (size_t)(b * S_ + i) * E_ + l * 16);
        op[0] = u0; op[1] = u1; op[2] = u2; op[3] = u3;
    }
}

extern "C" void kernel_launch(void* const* d_in, const int* in_sizes, int n_in,
                              void* d_out, int out_size, void* d_ws, size_t ws_size,
                              hipStream_t stream) {
    const float* x   = (const float*)d_in[0];
    const int*   rnd = (const int*)d_in[1];
    const float* qw  = (const float*)d_in[2];
    const float* qb  = (const float*)d_in[3];
    const float* kw  = (const float*)d_in[4];
    const float* kb  = (const float*)d_in[5];
    const float* vw  = (const float*)d_in[6];
    const float* vb  = (const float*)d_in[7];
    const float* ow  = (const float*)d_in[8];
    const float* ob  = (const float*)d_in[9];
    float* out = (float*)d_out;

    char* ws = (char*)d_ws;
    unsigned short* xb    = (unsigned short*)(ws);                       // 8 MB (dead after QKV GEMM)
    unsigned short* wqkv  = (unsigned short*)(ws + 8388608);             // 6 MB
    unsigned short* wo    = (unsigned short*)(ws + 14680064);            // 2 MB
    unsigned short* qkv   = (unsigned short*)(ws + 16777216);            // 24 MB
    unsigned short* attn  = (unsigned short*)(ws + 41943040);            // 8 MB
    float*          gaccp = (float*)(ws);                                // 128 KB (overlaps dead xb)
    float*          gms   = (float*)(ws + 131072);                       // 4 KB

    const int M = B_ * S_;   // 4096

    {
        int total4 = (M * E_ + 4 * E_ * E_) / 4;
        convert_all<<<total4 / 256, 256, 0, stream>>>(x, qw, kw, vw, ow, xb, wqkv, wo);
    }

    // QKV GEMM: [4096][3072] bf16, BK=64 swizzled, fully-resident grid
    {
        dim3 grid(M / 128, 3 * E_ / 128);
        gemm_qkv<<<grid, 256, 0, stream>>>(xb, wqkv, qb, kb, vb, qkv, M, 3 * E_, E_);
    }

    // global chunks (512, streaming flash) + sparse rows (1024, streaming)
    attn_fused<<<512 + 1024, 256, 0, stream>>>(qkv, rnd, gaccp, gms, attn);

    // O GEMM -> fp32 out, 128x128 tile, fused global-row merge (no fin dispatch)
    {
        dim3 grid(M / 128, E_ / 128);
        gemm_o<<<grid, 256, 0, stream>>>(attn, wo, ob, gaccp, gms, out, M, E_, E_);
    }
}

// Round 16
// 160.145 us; speedup vs baseline: 1.0105x; 1.0059x over previous
//
#include <hip/hip_runtime.h>

#define B_  2
#define S_  2048
#define E_  1024
#define H_  16
#define D_  64
#define NGLOB 2
#define NRAND 3
#define WIN 3

typedef __bf16 bf16x8 __attribute__((ext_vector_type(8)));
typedef float  f32x4  __attribute__((ext_vector_type(4)));

__device__ __forceinline__ unsigned short f2bf(float f) {
    unsigned u = __builtin_bit_cast(unsigned, f);
    unsigned r = u + 0x7FFFu + ((u >> 16) & 1u);   // RNE
    return (unsigned short)(r >> 16);
}
__device__ __forceinline__ float bf2f(unsigned short u) {
    return __builtin_bit_cast(float, (unsigned)u << 16);
}

// async global->LDS 16B DMA. LDS dest is wave-uniform base + lane*16.
__device__ __forceinline__ void g2l16(const unsigned short* g, unsigned short* l) {
    __builtin_amdgcn_global_load_lds(
        (const __attribute__((address_space(1))) unsigned*)g,
        (__attribute__((address_space(3))) unsigned*)l, 16, 0, 0);
}

// ---------------- fused fp32 -> bf16 conversion for x + 4 weights ----------------
__global__ __launch_bounds__(256)
void convert_all(const float* __restrict__ x,  const float* __restrict__ qw,
                 const float* __restrict__ kw, const float* __restrict__ vw,
                 const float* __restrict__ ow,
                 unsigned short* __restrict__ xb, unsigned short* __restrict__ wqkv,
                 unsigned short* __restrict__ wo) {
    const int XN = (B_ * S_ * E_) / 4;      // 1048576
    const int WN = (E_ * E_) / 4;           // 262144
    int i = blockIdx.x * blockDim.x + threadIdx.x;
    int r, loc;
    if (i < XN) { r = 0; loc = i; }
    else        { int j = i - XN; r = 1 + (j >> 18); loc = j & (WN - 1); }
    const float* src = r == 0 ? x : r == 1 ? qw : r == 2 ? kw : r == 3 ? vw : ow;
    float4 f = ((const float4*)src)[loc];
    ushort4 u;
    u.x = f2bf(f.x); u.y = f2bf(f.y); u.z = f2bf(f.z); u.w = f2bf(f.w);
    ushort4* dst = r == 0 ? (ushort4*)xb : r == 4 ? (ushort4*)wo
                 : (ushort4*)wqkv + (size_t)(r - 1) * WN;
    dst[loc] = u;
}

// ---------------- QKV GEMM: BK=64, XOR-swizzled LDS -------------------------------
// R16: __launch_bounds__(256,4) — 4 blocks/CU (LDS 4x32KB=128KB fits; VGPR cap 128,
// est. use ~115-125 no-spill). Mechanism: the structure's ~20% stall is the
// vmcnt(0) drain at each K-step barrier; more resident blocks -> more implicit
// wave-level overlap (m114) across the drain. Single-variable vs R13.
__global__ __launch_bounds__(256, 4)
void gemm_qkv(const unsigned short* __restrict__ A,  // [M][K] bf16
              const unsigned short* __restrict__ W,  // [N][K] bf16
              const float* __restrict__ b0, const float* __restrict__ b1,
              const float* __restrict__ b2,
              unsigned short* __restrict__ Cb, int M, int N, int K) {
    __shared__ unsigned short sA[128 * 64];   // 16 KB
    __shared__ unsigned short sB[128 * 64];   // 16 KB
    const int t = threadIdx.x;
    const int lane = t & 63;
    const int wave = t >> 6;
    const int wm = wave >> 1, wn = wave & 1;
    const int lq = lane >> 4;
    const int lr = lane & 15;
    const int bm = blockIdx.x * 128;
    const int bn = blockIdx.y * 128;

    f32x4 acc[4][4] = {};

    for (int k0 = 0; k0 < K; k0 += 64) {
        const unsigned short* Abase = A + (size_t)bm * K + k0;
        const unsigned short* Wbase = W + (size_t)bn * K + k0;
        #pragma unroll
        for (int j = 0; j < 4; ++j) {             // 1024 chunks each
            int c = j * 256 + t;
            int row = c >> 3, cc = c & 7;
            int gcol = ((cc ^ (row & 7)) << 3);   // swizzled source col
            int dst = j * 2048 + wave * 512;      // wave-uniform elem offset
            g2l16(Abase + (size_t)row * K + gcol, sA + dst);
            g2l16(Wbase + (size_t)row * K + gcol, sB + dst);
        }
        __syncthreads();

        #pragma unroll
        for (int ks = 0; ks < 2; ++ks) {
            const int sw = (((ks << 2) + lq) ^ (lr & 7)) << 3;
            bf16x8 af[4], bfr[4];
            #pragma unroll
            for (int i = 0; i < 4; ++i)
                af[i] = *(const bf16x8*)&sA[(wm * 64 + i * 16 + lr) * 64 + sw];
            #pragma unroll
            for (int j = 0; j < 4; ++j)
                bfr[j] = *(const bf16x8*)&sB[(wn * 64 + j * 16 + lr) * 64 + sw];
            #pragma unroll
            for (int i = 0; i < 4; ++i)
                #pragma unroll
                for (int j = 0; j < 4; ++j)
                    acc[i][j] = __builtin_amdgcn_mfma_f32_16x16x32_bf16(af[i], bfr[j], acc[i][j], 0, 0, 0);
        }
        __syncthreads();
    }

    #pragma unroll
    for (int i = 0; i < 4; ++i) {
        int row0 = bm + wm * 64 + i * 16 + lq * 4;
        #pragma unroll
        for (int j = 0; j < 4; ++j) {
            int col = bn + wn * 64 + j * 16 + lr;
            const float* bp = col < E_ ? b0 : (col < 2 * E_ ? b1 : b2);
            float bv = bp[col & (E_ - 1)];
            #pragma unroll
            for (int r = 0; r < 4; ++r)
                Cb[(size_t)(row0 + r) * N + col] = f2bf(acc[i][j][r] + bv);
        }
    }
}

// ---------------- O GEMM: 128x128 tile, fused global-row merge --------------------
// Blocks with bm==0 / bm==2048 (sole consumers of attn rows {0,1} per batch)
// first compute the 8-chunk flash merge for their 2 global rows, write bf16 to
// attn, vmcnt(0)+barrier, then stage normally (self-read through own L2).
// 8 blocks per batch redundantly write IDENTICAL bytes — benign.
__global__ __launch_bounds__(256, 3)
void gemm_o(unsigned short* A,                      // attn (read + global-row write)
            const unsigned short* __restrict__ W,   // [N][K] bf16 (wo)
            const float* __restrict__ bias,
            const float* __restrict__ gaccp, const float* __restrict__ gms,
            float* __restrict__ Cf, int M, int N, int K) {
    __shared__ unsigned short sA[128 * 64];   // 16 KB
    __shared__ unsigned short sB[128 * 64];   // 16 KB
    const int t = threadIdx.x;
    const int lane = t & 63;
    const int wave = t >> 6;
    const int wm = wave >> 1, wn = wave & 1;
    const int lq = lane >> 4;
    const int lr = lane & 15;
    const int bm = blockIdx.x * 128;
    const int bn = blockIdx.y * 128;

    // ---- fused gattn_fin for this tile's global rows ----
    if (blockIdx.x == 0 || blockIdx.x == 16) {
        int b = blockIdx.x >> 4;
        #pragma unroll
        for (int r = 0; r < 8; ++r) {
            int oid = r * 256 + t;              // 0..2047 : i2*1024 + col
            int i2 = oid >> 10, col = oid & 1023;
            int h = col >> 6, d = col & 63;
            int tup = b * 32 + i2 * 16 + h;
            float Mx = -1e30f;
            #pragma unroll
            for (int c = 0; c < 8; ++c) Mx = fmaxf(Mx, gms[(tup * 8 + c) * 2]);
            float den = 0.f, num = 0.f;
            #pragma unroll
            for (int c = 0; c < 8; ++c) {
                float f = __expf(gms[(tup * 8 + c) * 2] - Mx);
                den += gms[(tup * 8 + c) * 2 + 1] * f;
                num += gaccp[(size_t)(tup * 8 + c) * D_ + d] * f;
            }
            A[(size_t)(b * S_ + i2) * E_ + col] = f2bf(num / den);
        }
        asm volatile("s_waitcnt vmcnt(0)" ::: "memory");
    }
    __syncthreads();

    f32x4 acc[4][4] = {};

    for (int k0 = 0; k0 < K; k0 += 64) {
        const unsigned short* Abase = A + (size_t)bm * K + k0;
        const unsigned short* Wbase = W + (size_t)bn * K + k0;
        #pragma unroll
        for (int j = 0; j < 4; ++j) {
            int c = j * 256 + t;
            int row = c >> 3, cc = c & 7;
            int gcol = ((cc ^ (row & 7)) << 3);
            int dst = j * 2048 + wave * 512;
            g2l16(Abase + (size_t)row * K + gcol, sA + dst);
            g2l16(Wbase + (size_t)row * K + gcol, sB + dst);
        }
        __syncthreads();

        #pragma unroll
        for (int ks = 0; ks < 2; ++ks) {
            const int sw = (((ks << 2) + lq) ^ (lr & 7)) << 3;
            bf16x8 af[4], bfr[4];
            #pragma unroll
            for (int i = 0; i < 4; ++i)
                af[i] = *(const bf16x8*)&sA[(wm * 64 + i * 16 + lr) * 64 + sw];
            #pragma unroll
            for (int j = 0; j < 4; ++j)
                bfr[j] = *(const bf16x8*)&sB[(wn * 64 + j * 16 + lr) * 64 + sw];
            #pragma unroll
            for (int i = 0; i < 4; ++i)
                #pragma unroll
                for (int j = 0; j < 4; ++j)
                    acc[i][j] = __builtin_amdgcn_mfma_f32_16x16x32_bf16(af[i], bfr[j], acc[i][j], 0, 0, 0);
        }
        __syncthreads();
    }

    #pragma unroll
    for (int i = 0; i < 4; ++i) {
        int row0 = bm + wm * 64 + i * 16 + lq * 4;
        #pragma unroll
        for (int j = 0; j < 4; ++j) {
            int col = bn + wn * 64 + j * 16 + lr;
            float bv = bias[col];
            #pragma unroll
            for (int r = 0; r < 4; ++r)
                Cf[(size_t)(row0 + r) * N + col] = acc[i][j][r] + bv;
        }
    }
}

// ---------------- fused: streaming global chunks + streaming sparse rows ---------
// R13 (best measured): global path single streaming pass — per iter load K-chunk
// AND V-chunk together (16 loads, one in-flight window), 3-shfl score reduce,
// 3-shfl wave-max, online (mM, sum, o[8]) rescale; one key-sub shfl reduction,
// ONE barrier, 4-wave flash merge to gms/gaccp. Sparse path: one wave per row,
// single streaming pass with online softmax (group-uniform rescale).
__global__ __launch_bounds__(256)
void attn_fused(const unsigned short* __restrict__ qkv,
                const int* __restrict__ rnd,
                float* __restrict__ gaccp, float* __restrict__ gms,
                unsigned short* __restrict__ attn) {
    const int NB = B_ * (S_ - 2);     // 4092
    int t = threadIdx.x;

    if (blockIdx.x < 512) {
        // ---- one (tuple, key-chunk) per block, single streaming pass ----
        int tup = blockIdx.x >> 3, seg = blockIdx.x & 7;
        int b = tup >> 5, i = (tup >> 4) & 1, h = tup & 15;
        int w = t >> 6, l = t & 63;
        __shared__ float redm[4], reds[4];
        __shared__ float ov[4][D_];

        // q chunk for this lane: 8 bf16 dims (l&7)*8.. of the head slice
        const bf16x8* qp = (const bf16x8*)(qkv + (size_t)(b * S_ + i) * 3072 + h * D_);
        bf16x8 qv = qp[l & 7];
        float qreg[8];
        #pragma unroll
        for (int j = 0; j < 8; ++j) qreg[j] = (float)qv[j];

        // lane = (ksb key-sub, dg dim-group); wave w covers keys [key0, +64)
        const int key0 = seg * 256 + w * 64;
        const int ksb = l >> 3, dg = l & 7;
        float mM = -1e30f, ssum = 0.f;
        float o[8] = {};
        #pragma unroll
        for (int it = 0; it < 8; ++it) {
            int key = key0 + it * 8 + ksb;
            const unsigned short* kr =
                qkv + (size_t)(b * S_ + key) * 3072 + E_ + h * D_ + dg * 8;
            bf16x8 kv = *(const bf16x8*)kr;          // K chunk
            bf16x8 vv = *(const bf16x8*)(kr + E_);   // V chunk, same key/dims
            float s = 0.f;
            #pragma unroll
            for (int j = 0; j < 8; ++j) s += qreg[j] * (float)kv[j];
            s += __shfl_xor(s, 1);
            s += __shfl_xor(s, 2);
            s += __shfl_xor(s, 4);
            s *= 0.125f;                             // score for key it*8+ksb (all dg lanes)
            float m_it = s;
            m_it = fmaxf(m_it, __shfl_xor(m_it, 8));
            m_it = fmaxf(m_it, __shfl_xor(m_it, 16));
            m_it = fmaxf(m_it, __shfl_xor(m_it, 32));
            if (m_it > mM) {                         // wave-uniform
                float r = __expf(mM - m_it);
                ssum *= r;
                #pragma unroll
                for (int e2 = 0; e2 < 8; ++e2) o[e2] *= r;
                mM = m_it;
            }
            float e = __expf(s - mM);
            ssum += e;
            #pragma unroll
            for (int e2 = 0; e2 < 8; ++e2) o[e2] += e * (float)vv[e2];
        }
        // reduce over key-subs (masks vary ksb, keep dg)
        #pragma unroll
        for (int mask = 8; mask <= 32; mask <<= 1) {
            ssum += __shfl_xor(ssum, mask);
            #pragma unroll
            for (int e2 = 0; e2 < 8; ++e2) o[e2] += __shfl_xor(o[e2], mask);
        }
        if (l == 0) { redm[w] = mM; reds[w] = ssum; }
        if (ksb == 0)
            #pragma unroll
            for (int e2 = 0; e2 < 8; ++e2) ov[w][dg * 8 + e2] = o[e2];
        __syncthreads();
        if (w == 0) {
            float M = fmaxf(fmaxf(redm[0], redm[1]), fmaxf(redm[2], redm[3]));
            float f0 = __expf(redm[0] - M), f1 = __expf(redm[1] - M);
            float f2 = __expf(redm[2] - M), f3 = __expf(redm[3] - M);
            gaccp[((size_t)tup * 8 + seg) * D_ + l] =
                ov[0][l] * f0 + ov[1][l] * f1 + ov[2][l] * f2 + ov[3][l] * f3;
            if (l == 0) {
                gms[(tup * 8 + seg) * 2]     = M;
                gms[(tup * 8 + seg) * 2 + 1] =
                    reds[0] * f0 + reds[1] * f1 + reds[2] * f2 + reds[3] * f3;
            }
        }
        return;
    }

    // ---- sparse rows: one wave per row, single streaming pass ----
    int bb = blockIdx.x - 512;                        // [0,1024)
    int bidx = (bb & 7) * 128 + (bb >> 3);            // XCD swizzle
    int w = t >> 6, l = t & 63;
    int row = bidx * 4 + w;
    bool valid = row < NB;
    int b = row / (S_ - 2);
    int i = row % (S_ - 2) + 2;
    if (!valid) { b = 0; i = 2; }

    __shared__ int cols_s[4][12];
    __shared__ int ncol_sh[4];

    const bf16x8* qp = (const bf16x8*)(qkv + (size_t)(b * S_ + i) * 3072);
    bf16x8 q0 = qp[l * 2], q1 = qp[l * 2 + 1];
    float qreg[16];
    #pragma unroll
    for (int j = 0; j < 8; ++j) { qreg[j] = (float)q0[j]; qreg[8 + j] = (float)q1[j]; }

    if (l == 0) {
        int* cols = cols_s[w];
        int n = 0;
        cols[n++] = 0; cols[n++] = 1;
        int lo = i - WIN; if (lo < NGLOB) lo = NGLOB;
        int hi = i + WIN; if (hi > S_ - 1) hi = S_ - 1;
        for (int j = lo; j <= hi; ++j) cols[n++] = j;
        for (int r = 0; r < NRAND; ++r) {
            int c = rnd[i * NRAND + r];
            bool dup = false;
            for (int q = 0; q < n; ++q) dup = dup || (cols[q] == c);
            if (!dup) cols[n++] = c;
        }
        ncol_sh[w] = n;
        for (int q = n; q < 12; ++q) cols[q] = 0;
    }
    __syncthreads();
    const int n = ncol_sh[w];

    // streaming online-softmax: K and V of each candidate load together;
    // running (mM, ssum, o[16]) with 4-lane-group-uniform rescale.
    float mM = -1e30f, ssum = 0.f;
    float o[16] = {};
    #pragma unroll
    for (int c = 0; c < 12; ++c) {
        const unsigned short* base = qkv + (size_t)(b * S_ + cols_s[w][c]) * 3072 + E_;
        const bf16x8* kp = (const bf16x8*)base;
        bf16x8 k0 = kp[l * 2], k1 = kp[l * 2 + 1];
        const bf16x8* vp = (const bf16x8*)(base + E_);
        bf16x8 v0 = vp[l * 2], v1 = vp[l * 2 + 1];
        float s = 0.f;
        #pragma unroll
        for (int j = 0; j < 8; ++j) s += qreg[j] * (float)k0[j] + qreg[8 + j] * (float)k1[j];
        s += __shfl_xor(s, 1);
        s += __shfl_xor(s, 2);
        s = (c < n) ? s * 0.125f : -1e30f;
        if (s > mM) {                         // group-uniform (s identical in 4-lane group)
            float r = __expf(mM - s);
            ssum *= r;
            #pragma unroll
            for (int j = 0; j < 16; ++j) o[j] *= r;
            mM = s;
        }
        float e = __expf(s - mM);
        ssum += e;
        #pragma unroll
        for (int j = 0; j < 8; ++j) { o[j] += e * (float)v0[j]; o[8 + j] += e * (float)v1[j]; }
    }
    float inv = 1.f / ssum;
    #pragma unroll
    for (int j = 0; j < 16; ++j) o[j] *= inv;

    if (valid) {
        ushort4 u0, u1, u2, u3;
        u0.x = f2bf(o[0]);  u0.y = f2bf(o[1]);  u0.z = f2bf(o[2]);  u0.w = f2bf(o[3]);
        u1.x = f2bf(o[4]);  u1.y = f2bf(o[5]);  u1.z = f2bf(o[6]);  u1.w = f2bf(o[7]);
        u2.x = f2bf(o[8]);  u2.y = f2bf(o[9]);  u2.z = f2bf(o[10]); u2.w = f2bf(o[11]);
        u3.x = f2bf(o[12]); u3.y = f2bf(o[13]); u3.z = f2bf(o[14]); u3.w = f2bf(o[15]);
        ushort4* op = (ushort4*)(attn + (size_t)(b * S_ + i) * E_ + l * 16);
        op[0] = u0; op[1] = u1; op[2] = u2; op[3] = u3;
    }
}

extern "C" void kernel_launch(void* const* d_in, const int* in_sizes, int n_in,
                              void* d_out, int out_size, void* d_ws, size_t ws_size,
                              hipStream_t stream) {
    const float* x   = (const float*)d_in[0];
    const int*   rnd = (const int*)d_in[1];
    const float* qw  = (const float*)d_in[2];
    const float* qb  = (const float*)d_in[3];
    const float* kw  = (const float*)d_in[4];
    const float* kb  = (const float*)d_in[5];
    const float* vw  = (const float*)d_in[6];
    const float* vb  = (const float*)d_in[7];
    const float* ow  = (const float*)d_in[8];
    const float* ob  = (const float*)d_in[9];
    float* out = (float*)d_out;

    char* ws = (char*)d_ws;
    unsigned short* xb    = (unsigned short*)(ws);                       // 8 MB (dead after QKV GEMM)
    unsigned short* wqkv  = (unsigned short*)(ws + 8388608);             // 6 MB
    unsigned short* wo    = (unsigned short*)(ws + 14680064);            // 2 MB
    unsigned short* qkv   = (unsigned short*)(ws + 16777216);            // 24 MB
    unsigned short* attn  = (unsigned short*)(ws + 41943040);            // 8 MB
    float*          gaccp = (float*)(ws);                                // 128 KB (overlaps dead xb)
    float*          gms   = (float*)(ws + 131072);                       // 4 KB

    const int M = B_ * S_;   // 4096

    {
        int total4 = (M * E_ + 4 * E_ * E_) / 4;
        convert_all<<<total4 / 256, 256, 0, stream>>>(x, qw, kw, vw, ow, xb, wqkv, wo);
    }

    // QKV GEMM: [4096][3072] bf16, BK=64 swizzled, 4 blocks/CU (R16)
    {
        dim3 grid(M / 128, 3 * E_ / 128);
        gemm_qkv<<<grid, 256, 0, stream>>>(xb, wqkv, qb, kb, vb, qkv, M, 3 * E_, E_);
    }

    // global chunks (512, streaming flash) + sparse rows (1024, streaming)
    attn_fused<<<512 + 1024, 256, 0, stream>>>(qkv, rnd, gaccp, gms, attn);

    // O GEMM -> fp32 out, 128x128 tile, fused global-row merge (no fin dispatch)
    {
        dim3 grid(M / 128, E_ / 128);
        gemm_o<<<grid, 256, 0, stream>>>(attn, wo, ob, gaccp, gms, out, M, E_, E_);
    }
}